// Round 1
// baseline (139.073 us; speedup 1.0000x reference)
//
#include <hip/hip_runtime.h>

// EdgeLoss: mean |sobel_mag(gray(pred)) - sobel_mag(gray(target))|
// Inputs: prediction [16,3,512,512] f32, target [16,3,512,512] f32.
// Output: scalar f32.

constexpr int B = 16;
constexpr int H = 512;
constexpr int W = 512;
constexpr int TH = 32;            // tile height (output rows per block)
constexpr int TW = 64;            // tile width
constexpr int HALO_H = TH + 2;    // 34
constexpr int HALO_W = TW + 2;    // 66 (odd-ish stride -> no LDS bank conflicts)
constexpr int NTHREADS = 256;
constexpr int TILES_W = W / TW;           // 8
constexpr int TILES_H = H / TH;           // 16
constexpr int TILES_PER_IMG = TILES_W * TILES_H;  // 128
constexpr int NBLOCKS = B * TILES_PER_IMG;        // 2048
constexpr float EPS = 1e-6f;

__device__ __forceinline__ float gray_at(const float* __restrict__ img, int h, int w) {
    // img points at the start of one [3,H,W] image
    const float* p = img + (size_t)h * W + w;
    const size_t plane = (size_t)H * W;
    return 0.299f * p[0] + 0.587f * p[plane] + 0.114f * p[2 * plane];
}

__global__ __launch_bounds__(NTHREADS) void edge_loss_kernel(
    const float* __restrict__ pred,
    const float* __restrict__ targ,
    float* __restrict__ out)
{
    __shared__ float sp[HALO_H][HALO_W];
    __shared__ float st[HALO_H][HALO_W];

    const int bid = blockIdx.x;
    const int b   = bid / TILES_PER_IMG;
    const int t   = bid % TILES_PER_IMG;
    const int th0 = (t / TILES_W) * TH;
    const int tw0 = (t % TILES_W) * TW;
    const int tid = threadIdx.x;

    const float* __restrict__ pimg = pred + (size_t)b * 3 * H * W;
    const float* __restrict__ timg = targ + (size_t)b * 3 * H * W;

    // ---- Stage grayscale tile + halo (replicate padding via clamp) ----
    for (int i = tid; i < HALO_H * HALO_W; i += NTHREADS) {
        const int lh = i / HALO_W;
        const int lw = i - lh * HALO_W;
        const int gh = min(max(th0 + lh - 1, 0), H - 1);
        const int gw = min(max(tw0 + lw - 1, 0), W - 1);
        sp[lh][lw] = gray_at(pimg, gh, gw);
        st[lh][lw] = gray_at(timg, gh, gw);
    }
    __syncthreads();

    // ---- Sobel magnitude + |pe - te|, accumulate ----
    float acc = 0.0f;
    #pragma unroll
    for (int r = 0; r < (TH * TW) / NTHREADS; ++r) {
        const int i  = tid + r * NTHREADS;
        const int lh = i >> 6;          // i / TW (TW == 64)
        const int lw = i & 63;          // i % TW

        // prediction (halo coords: output pixel at [lh+1][lw+1])
        {
            const float p00 = sp[lh    ][lw], p01 = sp[lh    ][lw + 1], p02 = sp[lh    ][lw + 2];
            const float p10 = sp[lh + 1][lw],                            p12 = sp[lh + 1][lw + 2];
            const float p20 = sp[lh + 2][lw], p21 = sp[lh + 2][lw + 1], p22 = sp[lh + 2][lw + 2];
            const float gx = 0.125f * ((p02 - p00) + 2.0f * (p12 - p10) + (p22 - p20));
            const float gy = 0.125f * ((p20 - p00) + 2.0f * (p21 - p01) + (p22 - p02));
            const float pe = sqrtf(gx * gx + gy * gy + EPS);

            const float q00 = st[lh    ][lw], q01 = st[lh    ][lw + 1], q02 = st[lh    ][lw + 2];
            const float q10 = st[lh + 1][lw],                            q12 = st[lh + 1][lw + 2];
            const float q20 = st[lh + 2][lw], q21 = st[lh + 2][lw + 1], q22 = st[lh + 2][lw + 2];
            const float hx = 0.125f * ((q02 - q00) + 2.0f * (q12 - q10) + (q22 - q20));
            const float hy = 0.125f * ((q20 - q00) + 2.0f * (q21 - q01) + (q22 - q02));
            const float te = sqrtf(hx * hx + hy * hy + EPS);

            acc += fabsf(pe - te);
        }
    }

    // ---- Block reduction: wave64 shuffle, then LDS across 4 waves ----
    #pragma unroll
    for (int off = 32; off > 0; off >>= 1)
        acc += __shfl_down(acc, off);

    __shared__ float wsum[NTHREADS / 64];
    if ((tid & 63) == 0) wsum[tid >> 6] = acc;
    __syncthreads();

    if (tid == 0) {
        float s = wsum[0] + wsum[1] + wsum[2] + wsum[3];
        // 1 / (16*512*512) = 2^-22, exact in fp32
        atomicAdd(out, s * (1.0f / (float)((size_t)B * H * W)));
    }
}

extern "C" void kernel_launch(void* const* d_in, const int* in_sizes, int n_in,
                              void* d_out, int out_size, void* d_ws, size_t ws_size,
                              hipStream_t stream) {
    const float* pred = (const float*)d_in[0];
    const float* targ = (const float*)d_in[1];
    float* out = (float*)d_out;

    // d_out is poisoned to 0xAA before every timed launch -> zero it first.
    hipMemsetAsync(out, 0, sizeof(float), stream);
    edge_loss_kernel<<<NBLOCKS, NTHREADS, 0, stream>>>(pred, targ, out);
}

// Round 2
// 134.633 us; speedup vs baseline: 1.0330x; 1.0330x over previous
//
#include <hip/hip_runtime.h>

// EdgeLoss: mean |sobel_mag(gray(pred)) - sobel_mag(gray(target))|
// Inputs: prediction [16,3,512,512] f32, target [16,3,512,512] f32. Output: scalar f32.
// HBM-bound: 100.7 MB read once -> ~16 us floor at 6.3 TB/s.

constexpr int B = 16;
constexpr int H = 512;
constexpr int W = 512;
constexpr int TH = 32;             // output rows per block
constexpr int TW = 64;             // output cols per block
constexpr int HROWS = TH + 2;      // 34 halo rows
constexpr int LSTRIDE = 72;        // LDS row stride (floats); center cols at [4..67] -> 16B aligned
constexpr int NTHREADS = 256;
constexpr int TILES_W = W / TW;            // 8
constexpr int TILES_H = H / TH;            // 16
constexpr int TILES_PER_IMG = TILES_W * TILES_H;   // 128
constexpr int NBLOCKS = B * TILES_PER_IMG;         // 2048
constexpr int NGRP = HROWS * (TW / 4);             // 544 center float4-groups
constexpr float EPS = 1e-6f;

__device__ __forceinline__ float4 ldg4(const float* p) {
    return *reinterpret_cast<const float4*>(p);
}

__global__ __launch_bounds__(NTHREADS) void edge_loss_kernel(
    const float* __restrict__ pred,
    const float* __restrict__ targ,
    float* __restrict__ out)
{
    __shared__ alignas(16) float sp[HROWS][LSTRIDE];
    __shared__ alignas(16) float st[HROWS][LSTRIDE];

    const int bid = blockIdx.x;
    const int b   = bid / TILES_PER_IMG;
    const int t   = bid % TILES_PER_IMG;
    const int th0 = (t / TILES_W) * TH;
    const int tw0 = (t % TILES_W) * TW;
    const int tid = threadIdx.x;
    const size_t plane = (size_t)H * W;

    const float* __restrict__ pimg = pred + (size_t)b * 3 * plane;
    const float* __restrict__ timg = targ + (size_t)b * 3 * plane;

    // ---- Stage center columns as float4: 6 independent 16B loads per iter ----
    for (int g = tid; g < NGRP; g += NTHREADS) {
        const int row  = g >> 4;          // 0..33
        const int k    = g & 15;          // float4 group within row
        const int grow = min(max(th0 - 1 + row, 0), H - 1);
        const float* pp = pimg + (size_t)grow * W + (tw0 + 4 * k);
        const float* tp = timg + (size_t)grow * W + (tw0 + 4 * k);
        const float4 pr = ldg4(pp);
        const float4 pg = ldg4(pp + plane);
        const float4 pb = ldg4(pp + 2 * plane);
        const float4 tr = ldg4(tp);
        const float4 tg = ldg4(tp + plane);
        const float4 tb = ldg4(tp + 2 * plane);
        float4 gp, gt;
        gp.x = 0.299f * pr.x + 0.587f * pg.x + 0.114f * pb.x;
        gp.y = 0.299f * pr.y + 0.587f * pg.y + 0.114f * pb.y;
        gp.z = 0.299f * pr.z + 0.587f * pg.z + 0.114f * pb.z;
        gp.w = 0.299f * pr.w + 0.587f * pg.w + 0.114f * pb.w;
        gt.x = 0.299f * tr.x + 0.587f * tg.x + 0.114f * tb.x;
        gt.y = 0.299f * tr.y + 0.587f * tg.y + 0.114f * tb.y;
        gt.z = 0.299f * tr.z + 0.587f * tg.z + 0.114f * tb.z;
        gt.w = 0.299f * tr.w + 0.587f * tg.w + 0.114f * tb.w;
        *reinterpret_cast<float4*>(&sp[row][4 + 4 * k]) = gp;
        *reinterpret_cast<float4*>(&st[row][4 + 4 * k]) = gt;
    }

    // ---- Stage the two halo edge columns (replicate-clamped), scalar ----
    if (tid < 4 * HROWS) {                 // 136 tasks
        const int img  = tid & 1;
        const int rr   = tid >> 1;         // 0..67
        const int side = rr >= HROWS;
        const int row  = side ? rr - HROWS : rr;
        const int grow = min(max(th0 - 1 + row, 0), H - 1);
        const int gcol = side ? min(tw0 + TW, W - 1) : max(tw0 - 1, 0);
        const float* ip = (img ? timg : pimg) + (size_t)grow * W + gcol;
        const float v = 0.299f * ip[0] + 0.587f * ip[plane] + 0.114f * ip[2 * plane];
        float (*dst)[LSTRIDE] = img ? st : sp;
        dst[row][side ? 68 : 3] = v;
    }
    __syncthreads();

    // ---- Compute: vertical rolling 3x3 window, 8 rows per thread ----
    // wave w handles rows [8w .. 8w+7], lane = column. Conflict-free LDS reads.
    const int lw = tid & 63;               // column within tile
    const int q  = tid >> 6;               // wave index = vertical quarter
    const int r0 = q * 8;                  // first output row (halo row r0 is top)
    const int c0 = lw + 3, c1 = lw + 4, c2 = lw + 5;  // LDS cols (left,mid,right)

    float pa0 = sp[r0][c0],     pa1 = sp[r0][c1],     pa2 = sp[r0][c2];
    float pb0 = sp[r0 + 1][c0], pb1 = sp[r0 + 1][c1], pb2 = sp[r0 + 1][c2];
    float ta0 = st[r0][c0],     ta1 = st[r0][c1],     ta2 = st[r0][c2];
    float tb0 = st[r0 + 1][c0], tb1 = st[r0 + 1][c1], tb2 = st[r0 + 1][c2];

    float acc = 0.0f;
    #pragma unroll
    for (int r = 0; r < 8; ++r) {
        const int hr = r0 + r + 2;         // bottom halo row
        const float pc0 = sp[hr][c0], pc1 = sp[hr][c1], pc2 = sp[hr][c2];
        const float tc0 = st[hr][c0], tc1 = st[hr][c1], tc2 = st[hr][c2];

        float gx = ((pa2 - pa0) + 2.0f * (pb2 - pb0) + (pc2 - pc0)) * 0.125f;
        float gy = ((pc0 - pa0) + 2.0f * (pc1 - pa1) + (pc2 - pa2)) * 0.125f;
        const float pe = sqrtf(gx * gx + gy * gy + EPS);

        float hx = ((ta2 - ta0) + 2.0f * (tb2 - tb0) + (tc2 - tc0)) * 0.125f;
        float hy = ((tc0 - ta0) + 2.0f * (tc1 - ta1) + (tc2 - ta2)) * 0.125f;
        const float te = sqrtf(hx * hx + hy * hy + EPS);

        acc += fabsf(pe - te);

        // rotate window down (SSA copies, free after regalloc)
        pa0 = pb0; pa1 = pb1; pa2 = pb2;
        pb0 = pc0; pb1 = pc1; pb2 = pc2;
        ta0 = tb0; ta1 = tb1; ta2 = tb2;
        tb0 = tc0; tb1 = tc1; tb2 = tc2;
    }

    // ---- Block reduction: wave64 shuffle, then LDS across 4 waves ----
    #pragma unroll
    for (int off = 32; off > 0; off >>= 1)
        acc += __shfl_down(acc, off);

    __shared__ float wsum[NTHREADS / 64];
    if ((tid & 63) == 0) wsum[tid >> 6] = acc;
    __syncthreads();

    if (tid == 0) {
        const float s = wsum[0] + wsum[1] + wsum[2] + wsum[3];
        atomicAdd(out, s * (1.0f / (float)((size_t)B * H * W)));  // 2^-22, exact
    }
}

extern "C" void kernel_launch(void* const* d_in, const int* in_sizes, int n_in,
                              void* d_out, int out_size, void* d_ws, size_t ws_size,
                              hipStream_t stream) {
    const float* pred = (const float*)d_in[0];
    const float* targ = (const float*)d_in[1];
    float* out = (float*)d_out;

    // d_out is poisoned to 0xAA before every timed launch -> zero it first.
    hipMemsetAsync(out, 0, sizeof(float), stream);
    edge_loss_kernel<<<NBLOCKS, NTHREADS, 0, stream>>>(pred, targ, out);
}

// Round 3
// 133.112 us; speedup vs baseline: 1.0448x; 1.0114x over previous
//
#include <hip/hip_runtime.h>

// EdgeLoss: mean |sobel_mag(gray(pred)) - sobel_mag(gray(target))|
// Inputs: prediction [16,3,512,512] f32, target [16,3,512,512] f32. Output: scalar f32.
// Latency-bound fix (R3): static-unrolled staging with 12 float4 loads in flight.

constexpr int B = 16;
constexpr int H = 512;
constexpr int W = 512;
constexpr int TH = 32;             // output rows per block
constexpr int TW = 64;             // output cols per block
constexpr int HROWS = TH + 2;      // 34 halo rows
constexpr int LSTRIDE = 72;        // LDS row stride (floats); center cols [4..67], 16B aligned
constexpr int NTHREADS = 256;
constexpr int TILES_W = W / TW;            // 8
constexpr int TILES_H = H / TH;            // 16
constexpr int TILES_PER_IMG = TILES_W * TILES_H;   // 128
constexpr int NBLOCKS = B * TILES_PER_IMG;         // 2048
constexpr float EPS = 1e-6f;

__device__ __forceinline__ float4 ldg4(const float* p) {
    return *reinterpret_cast<const float4*>(p);
}

__device__ __forceinline__ float4 gray4(float4 r, float4 g, float4 b) {
    float4 o;
    o.x = 0.299f * r.x + 0.587f * g.x + 0.114f * b.x;
    o.y = 0.299f * r.y + 0.587f * g.y + 0.114f * b.y;
    o.z = 0.299f * r.z + 0.587f * g.z + 0.114f * b.z;
    o.w = 0.299f * r.w + 0.587f * g.w + 0.114f * b.w;
    return o;
}

__global__ __launch_bounds__(NTHREADS) void edge_loss_kernel(
    const float* __restrict__ pred,
    const float* __restrict__ targ,
    float* __restrict__ out)
{
    __shared__ alignas(16) float sp[HROWS][LSTRIDE];
    __shared__ alignas(16) float st[HROWS][LSTRIDE];

    const int bid = blockIdx.x;
    const int b   = bid / TILES_PER_IMG;
    const int t   = bid % TILES_PER_IMG;
    const int th0 = (t / TILES_W) * TH;
    const int tw0 = (t % TILES_W) * TW;
    const int tid = threadIdx.x;
    const size_t plane = (size_t)H * W;

    // 6 wave-uniform channel base pointers -> saddr-form loads, 1 voffset per group
    const float* __restrict__ p0 = pred + (size_t)b * 3 * plane;
    const float* __restrict__ p1 = p0 + plane;
    const float* __restrict__ p2 = p0 + 2 * plane;
    const float* __restrict__ t0 = targ + (size_t)b * 3 * plane;
    const float* __restrict__ t1 = t0 + plane;
    const float* __restrict__ t2 = t0 + 2 * plane;

    // staging task g -> (row, k): row = g>>4 (0..33), k = g&15 (float4 col group)
    // NGRP = 34*16 = 544 = 256 (A) + 256 (B) + 32 (C, tid<32)
    const int rowA = tid >> 4, kA = tid & 15;
    const int gB = tid + 256;
    const int rowB = gB >> 4, kB = gB & 15;
    const int offA = (min(max(th0 - 1 + rowA, 0), H - 1)) * W + tw0 + 4 * kA;
    const int offB = (min(max(th0 - 1 + rowB, 0), H - 1)) * W + tw0 + 4 * kB;

    // ---- issue group A + group B loads back-to-back (12 x 16B in flight) ----
    const float4 Apr = ldg4(p0 + offA), Apg = ldg4(p1 + offA), Apb = ldg4(p2 + offA);
    const float4 Atr = ldg4(t0 + offA), Atg = ldg4(t1 + offA), Atb = ldg4(t2 + offA);
    const float4 Bpr = ldg4(p0 + offB), Bpg = ldg4(p1 + offB), Bpb = ldg4(p2 + offB);
    const float4 Btr = ldg4(t0 + offB), Btg = ldg4(t1 + offB), Btb = ldg4(t2 + offB);

    // ---- consume A (waits only for first 6; B stays outstanding) ----
    *reinterpret_cast<float4*>(&sp[rowA][4 + 4 * kA]) = gray4(Apr, Apg, Apb);
    *reinterpret_cast<float4*>(&st[rowA][4 + 4 * kA]) = gray4(Atr, Atg, Atb);

    // ---- halo edge columns (136 threads, scalar, overlaps with B in flight) ----
    if (tid < 4 * HROWS) {
        const int img  = tid & 1;
        const int rr   = tid >> 1;         // 0..67
        const int side = rr >= HROWS;
        const int row  = side ? rr - HROWS : rr;
        const int grow = min(max(th0 - 1 + row, 0), H - 1);
        const int gcol = side ? min(tw0 + TW, W - 1) : max(tw0 - 1, 0);
        const float* ip = (img ? t0 : p0) + (size_t)grow * W + gcol;
        const float v = 0.299f * ip[0] + 0.587f * ip[plane] + 0.114f * ip[2 * plane];
        float (*dst)[LSTRIDE] = img ? st : sp;
        dst[row][side ? 68 : 3] = v;
    }

    // ---- group C (rows 32..33, only tid<32) ----
    if (tid < 32) {
        const int gC = tid + 512;
        const int rowC = gC >> 4, kC = gC & 15;
        const int offC = (min(max(th0 - 1 + rowC, 0), H - 1)) * W + tw0 + 4 * kC;
        const float4 Cpr = ldg4(p0 + offC), Cpg = ldg4(p1 + offC), Cpb = ldg4(p2 + offC);
        const float4 Ctr = ldg4(t0 + offC), Ctg = ldg4(t1 + offC), Ctb = ldg4(t2 + offC);
        *reinterpret_cast<float4*>(&sp[rowC][4 + 4 * kC]) = gray4(Cpr, Cpg, Cpb);
        *reinterpret_cast<float4*>(&st[rowC][4 + 4 * kC]) = gray4(Ctr, Ctg, Ctb);
    }

    // ---- consume B ----
    *reinterpret_cast<float4*>(&sp[rowB][4 + 4 * kB]) = gray4(Bpr, Bpg, Bpb);
    *reinterpret_cast<float4*>(&st[rowB][4 + 4 * kB]) = gray4(Btr, Btg, Btb);

    __syncthreads();

    // ---- Compute: vertical rolling 3x3 window, 8 rows per thread ----
    const int lw = tid & 63;               // column within tile
    const int q  = tid >> 6;               // wave index = vertical quarter
    const int r0 = q * 8;                  // top halo row for this strip
    const int c0 = lw + 3, c1 = lw + 4, c2 = lw + 5;

    float pa0 = sp[r0][c0],     pa1 = sp[r0][c1],     pa2 = sp[r0][c2];
    float pb0 = sp[r0 + 1][c0], pb1 = sp[r0 + 1][c1], pb2 = sp[r0 + 1][c2];
    float ta0 = st[r0][c0],     ta1 = st[r0][c1],     ta2 = st[r0][c2];
    float tb0 = st[r0 + 1][c0], tb1 = st[r0 + 1][c1], tb2 = st[r0 + 1][c2];

    float acc = 0.0f;
    #pragma unroll
    for (int r = 0; r < 8; ++r) {
        const int hr = r0 + r + 2;
        const float pc0 = sp[hr][c0], pc1 = sp[hr][c1], pc2 = sp[hr][c2];
        const float tc0 = st[hr][c0], tc1 = st[hr][c1], tc2 = st[hr][c2];

        float gx = ((pa2 - pa0) + 2.0f * (pb2 - pb0) + (pc2 - pc0)) * 0.125f;
        float gy = ((pc0 - pa0) + 2.0f * (pc1 - pa1) + (pc2 - pa2)) * 0.125f;
        const float pe = sqrtf(gx * gx + gy * gy + EPS);

        float hx = ((ta2 - ta0) + 2.0f * (tb2 - tb0) + (tc2 - tc0)) * 0.125f;
        float hy = ((tc0 - ta0) + 2.0f * (tc1 - ta1) + (tc2 - ta2)) * 0.125f;
        const float te = sqrtf(hx * hx + hy * hy + EPS);

        acc += fabsf(pe - te);

        pa0 = pb0; pa1 = pb1; pa2 = pb2;
        pb0 = pc0; pb1 = pc1; pb2 = pc2;
        ta0 = tb0; ta1 = tb1; ta2 = tb2;
        tb0 = tc0; tb1 = tc1; tb2 = tc2;
    }

    // ---- Block reduction ----
    #pragma unroll
    for (int off = 32; off > 0; off >>= 1)
        acc += __shfl_down(acc, off);

    __shared__ float wsum[NTHREADS / 64];
    if ((tid & 63) == 0) wsum[tid >> 6] = acc;
    __syncthreads();

    if (tid == 0) {
        const float s = wsum[0] + wsum[1] + wsum[2] + wsum[3];
        atomicAdd(out, s * (1.0f / (float)((size_t)B * H * W)));  // 2^-22, exact
    }
}

extern "C" void kernel_launch(void* const* d_in, const int* in_sizes, int n_in,
                              void* d_out, int out_size, void* d_ws, size_t ws_size,
                              hipStream_t stream) {
    const float* pred = (const float*)d_in[0];
    const float* targ = (const float*)d_in[1];
    float* out = (float*)d_out;

    hipMemsetAsync(out, 0, sizeof(float), stream);
    edge_loss_kernel<<<NBLOCKS, NTHREADS, 0, stream>>>(pred, targ, out);
}

// Round 4
// 131.994 us; speedup vs baseline: 1.0536x; 1.0085x over previous
//
#include <hip/hip_runtime.h>

// EdgeLoss: mean |sobel_mag(gray(pred)) - sobel_mag(gray(target))|
// Inputs: prediction [16,3,512,512] f32, target [16,3,512,512] f32. Output: scalar f32.
// R4: __launch_bounds__(256,4) raises VGPR cap to 128 so all staging loads
// (A:6 + B:6 + halo:3 + C:6 float4/scalar) stay in flight before any consume.

constexpr int B = 16;
constexpr int H = 512;
constexpr int W = 512;
constexpr int TH = 32;             // output rows per block
constexpr int TW = 64;             // output cols per block
constexpr int HROWS = TH + 2;      // 34 halo rows
constexpr int LSTRIDE = 72;        // LDS row stride (floats); center cols [4..67], 16B aligned
constexpr int NTHREADS = 256;
constexpr int TILES_W = W / TW;            // 8
constexpr int TILES_H = H / TH;            // 16
constexpr int TILES_PER_IMG = TILES_W * TILES_H;   // 128
constexpr int NBLOCKS = B * TILES_PER_IMG;         // 2048
constexpr float EPS = 1e-6f;

__device__ __forceinline__ float4 ldg4(const float* p) {
    return *reinterpret_cast<const float4*>(p);
}

__device__ __forceinline__ float4 gray4(float4 r, float4 g, float4 b) {
    float4 o;
    o.x = 0.299f * r.x + 0.587f * g.x + 0.114f * b.x;
    o.y = 0.299f * r.y + 0.587f * g.y + 0.114f * b.y;
    o.z = 0.299f * r.z + 0.587f * g.z + 0.114f * b.z;
    o.w = 0.299f * r.w + 0.587f * g.w + 0.114f * b.w;
    return o;
}

// 4 waves/EU (=16 waves/CU for 256-thread blocks) -> VGPR cap 128:
// enough to hold ~19 in-flight loads instead of regalloc serializing them.
__global__ __launch_bounds__(NTHREADS, 4) void edge_loss_kernel(
    const float* __restrict__ pred,
    const float* __restrict__ targ,
    float* __restrict__ out)
{
    __shared__ alignas(16) float sp[HROWS][LSTRIDE];
    __shared__ alignas(16) float st[HROWS][LSTRIDE];

    const int bid = blockIdx.x;
    const int b   = bid / TILES_PER_IMG;
    const int t   = bid % TILES_PER_IMG;
    const int th0 = (t / TILES_W) * TH;
    const int tw0 = (t % TILES_W) * TW;
    const int tid = threadIdx.x;
    const size_t plane = (size_t)H * W;

    const float* __restrict__ p0 = pred + (size_t)b * 3 * plane;
    const float* __restrict__ p1 = p0 + plane;
    const float* __restrict__ p2 = p0 + 2 * plane;
    const float* __restrict__ t0 = targ + (size_t)b * 3 * plane;
    const float* __restrict__ t1 = t0 + plane;
    const float* __restrict__ t2 = t0 + 2 * plane;

    // staging task g -> (row, k): row = g>>4 (0..33), k = g&15 (float4 col group)
    // NGRP = 34*16 = 544 = 256 (A) + 256 (B) + 32 (C, tid<32)
    const int rowA = tid >> 4, kA = tid & 15;
    const int gB = tid + 256;
    const int rowB = gB >> 4, kB = gB & 15;
    const int offA = (min(max(th0 - 1 + rowA, 0), H - 1)) * W + tw0 + 4 * kA;
    const int offB = (min(max(th0 - 1 + rowB, 0), H - 1)) * W + tw0 + 4 * kB;

    // ---- issue ALL loads before ANY consume ----
    const float4 Apr = ldg4(p0 + offA), Apg = ldg4(p1 + offA), Apb = ldg4(p2 + offA);
    const float4 Atr = ldg4(t0 + offA), Atg = ldg4(t1 + offA), Atb = ldg4(t2 + offA);
    const float4 Bpr = ldg4(p0 + offB), Bpg = ldg4(p1 + offB), Bpb = ldg4(p2 + offB);
    const float4 Btr = ldg4(t0 + offB), Btg = ldg4(t1 + offB), Btb = ldg4(t2 + offB);

    // halo edge columns (tid<136): 3 scalar loads, value computed later
    float hv0 = 0.f, hv1 = 0.f, hv2 = 0.f;
    int hrow = 0, hside = 0, himg = 0;
    if (tid < 4 * HROWS) {
        himg = tid & 1;
        const int rr = tid >> 1;           // 0..67
        hside = rr >= HROWS;
        hrow  = hside ? rr - HROWS : rr;
        const int grow = min(max(th0 - 1 + hrow, 0), H - 1);
        const int gcol = hside ? min(tw0 + TW, W - 1) : max(tw0 - 1, 0);
        const float* ip = (himg ? t0 : p0) + (size_t)grow * W + gcol;
        hv0 = ip[0]; hv1 = ip[plane]; hv2 = ip[2 * plane];
    }

    // group C (rows 32..33, tid<32)
    float4 Cpr, Cpg, Cpb, Ctr, Ctg, Ctb;
    int rowC = 0, kC = 0;
    if (tid < 32) {
        const int gC = tid + 512;
        rowC = gC >> 4; kC = gC & 15;
        const int offC = (min(max(th0 - 1 + rowC, 0), H - 1)) * W + tw0 + 4 * kC;
        Cpr = ldg4(p0 + offC); Cpg = ldg4(p1 + offC); Cpb = ldg4(p2 + offC);
        Ctr = ldg4(t0 + offC); Ctg = ldg4(t1 + offC); Ctb = ldg4(t2 + offC);
    }

    // ---- consume (in issue order; vmcnt drains progressively) ----
    *reinterpret_cast<float4*>(&sp[rowA][4 + 4 * kA]) = gray4(Apr, Apg, Apb);
    *reinterpret_cast<float4*>(&st[rowA][4 + 4 * kA]) = gray4(Atr, Atg, Atb);
    *reinterpret_cast<float4*>(&sp[rowB][4 + 4 * kB]) = gray4(Bpr, Bpg, Bpb);
    *reinterpret_cast<float4*>(&st[rowB][4 + 4 * kB]) = gray4(Btr, Btg, Btb);

    if (tid < 4 * HROWS) {
        const float v = 0.299f * hv0 + 0.587f * hv1 + 0.114f * hv2;
        float (*dst)[LSTRIDE] = himg ? st : sp;
        dst[hrow][hside ? 68 : 3] = v;
    }
    if (tid < 32) {
        *reinterpret_cast<float4*>(&sp[rowC][4 + 4 * kC]) = gray4(Cpr, Cpg, Cpb);
        *reinterpret_cast<float4*>(&st[rowC][4 + 4 * kC]) = gray4(Ctr, Ctg, Ctb);
    }

    __syncthreads();

    // ---- Compute: vertical rolling 3x3 window, 8 rows per thread ----
    const int lw = tid & 63;               // column within tile
    const int q  = tid >> 6;               // wave index = vertical quarter
    const int r0 = q * 8;                  // top halo row for this strip
    const int c0 = lw + 3, c1 = lw + 4, c2 = lw + 5;

    float pa0 = sp[r0][c0],     pa1 = sp[r0][c1],     pa2 = sp[r0][c2];
    float pb0 = sp[r0 + 1][c0], pb1 = sp[r0 + 1][c1], pb2 = sp[r0 + 1][c2];
    float ta0 = st[r0][c0],     ta1 = st[r0][c1],     ta2 = st[r0][c2];
    float tb0 = st[r0 + 1][c0], tb1 = st[r0 + 1][c1], tb2 = st[r0 + 1][c2];

    float acc = 0.0f;
    #pragma unroll
    for (int r = 0; r < 8; ++r) {
        const int hr = r0 + r + 2;
        const float pc0 = sp[hr][c0], pc1 = sp[hr][c1], pc2 = sp[hr][c2];
        const float tc0 = st[hr][c0], tc1 = st[hr][c1], tc2 = st[hr][c2];

        float gx = ((pa2 - pa0) + 2.0f * (pb2 - pb0) + (pc2 - pc0)) * 0.125f;
        float gy = ((pc0 - pa0) + 2.0f * (pc1 - pa1) + (pc2 - pa2)) * 0.125f;
        const float pe = sqrtf(gx * gx + gy * gy + EPS);

        float hx = ((ta2 - ta0) + 2.0f * (tb2 - tb0) + (tc2 - tc0)) * 0.125f;
        float hy = ((tc0 - ta0) + 2.0f * (tc1 - ta1) + (tc2 - ta2)) * 0.125f;
        const float te = sqrtf(hx * hx + hy * hy + EPS);

        acc += fabsf(pe - te);

        pa0 = pb0; pa1 = pb1; pa2 = pb2;
        pb0 = pc0; pb1 = pc1; pb2 = pc2;
        ta0 = tb0; ta1 = tb1; ta2 = tb2;
        tb0 = tc0; tb1 = tc1; tb2 = tc2;
    }

    // ---- Block reduction ----
    #pragma unroll
    for (int off = 32; off > 0; off >>= 1)
        acc += __shfl_down(acc, off);

    __shared__ float wsum[NTHREADS / 64];
    if ((tid & 63) == 0) wsum[tid >> 6] = acc;
    __syncthreads();

    if (tid == 0) {
        const float s = wsum[0] + wsum[1] + wsum[2] + wsum[3];
        atomicAdd(out, s * (1.0f / (float)((size_t)B * H * W)));  // 2^-22, exact
    }
}

extern "C" void kernel_launch(void* const* d_in, const int* in_sizes, int n_in,
                              void* d_out, int out_size, void* d_ws, size_t ws_size,
                              hipStream_t stream) {
    const float* pred = (const float*)d_in[0];
    const float* targ = (const float*)d_in[1];
    float* out = (float*)d_out;

    hipMemsetAsync(out, 0, sizeof(float), stream);
    edge_loss_kernel<<<NBLOCKS, NTHREADS, 0, stream>>>(pred, targ, out);
}

// Round 5
// 123.068 us; speedup vs baseline: 1.1301x; 1.0725x over previous
//
#include <hip/hip_runtime.h>

// EdgeLoss: mean |sobel_mag(gray(pred)) - sobel_mag(gray(target))|
// Inputs: prediction [16,3,512,512] f32, target [16,3,512,512] f32. Output: scalar f32.
// R5: remove the 2048-blocks -> 1-address atomicAdd tail (measured-invariant
// ~44us floor across memory residence). Blocks store partials to d_ws; a tiny
// second kernel reduces 2048 floats and writes d_out.

constexpr int B = 16;
constexpr int H = 512;
constexpr int W = 512;
constexpr int TH = 32;             // output rows per block
constexpr int TW = 64;             // output cols per block
constexpr int HROWS = TH + 2;      // 34 halo rows
constexpr int LSTRIDE = 72;        // LDS row stride (floats); center cols [4..67], 16B aligned
constexpr int NTHREADS = 256;
constexpr int TILES_W = W / TW;            // 8
constexpr int TILES_H = H / TH;            // 16
constexpr int TILES_PER_IMG = TILES_W * TILES_H;   // 128
constexpr int NBLOCKS = B * TILES_PER_IMG;         // 2048
constexpr float EPS = 1e-6f;

__device__ __forceinline__ float4 ldg4(const float* p) {
    return *reinterpret_cast<const float4*>(p);
}

__device__ __forceinline__ float4 gray4(float4 r, float4 g, float4 b) {
    float4 o;
    o.x = 0.299f * r.x + 0.587f * g.x + 0.114f * b.x;
    o.y = 0.299f * r.y + 0.587f * g.y + 0.114f * b.y;
    o.z = 0.299f * r.z + 0.587f * g.z + 0.114f * b.z;
    o.w = 0.299f * r.w + 0.587f * g.w + 0.114f * b.w;
    return o;
}

__global__ __launch_bounds__(NTHREADS, 4) void edge_loss_kernel(
    const float* __restrict__ pred,
    const float* __restrict__ targ,
    float* __restrict__ partial)
{
    __shared__ alignas(16) float sp[HROWS][LSTRIDE];
    __shared__ alignas(16) float st[HROWS][LSTRIDE];

    const int bid = blockIdx.x;
    const int b   = bid / TILES_PER_IMG;
    const int t   = bid % TILES_PER_IMG;
    const int th0 = (t / TILES_W) * TH;
    const int tw0 = (t % TILES_W) * TW;
    const int tid = threadIdx.x;
    const size_t plane = (size_t)H * W;

    const float* __restrict__ p0 = pred + (size_t)b * 3 * plane;
    const float* __restrict__ p1 = p0 + plane;
    const float* __restrict__ p2 = p0 + 2 * plane;
    const float* __restrict__ t0 = targ + (size_t)b * 3 * plane;
    const float* __restrict__ t1 = t0 + plane;
    const float* __restrict__ t2 = t0 + 2 * plane;

    // staging task g -> (row, k): row = g>>4 (0..33), k = g&15 (float4 col group)
    // NGRP = 34*16 = 544 = 256 (A) + 256 (B) + 32 (C, tid<32)
    const int rowA = tid >> 4, kA = tid & 15;
    const int gB = tid + 256;
    const int rowB = gB >> 4, kB = gB & 15;
    const int offA = (min(max(th0 - 1 + rowA, 0), H - 1)) * W + tw0 + 4 * kA;
    const int offB = (min(max(th0 - 1 + rowB, 0), H - 1)) * W + tw0 + 4 * kB;

    // ---- issue ALL loads before ANY consume ----
    const float4 Apr = ldg4(p0 + offA), Apg = ldg4(p1 + offA), Apb = ldg4(p2 + offA);
    const float4 Atr = ldg4(t0 + offA), Atg = ldg4(t1 + offA), Atb = ldg4(t2 + offA);
    const float4 Bpr = ldg4(p0 + offB), Bpg = ldg4(p1 + offB), Bpb = ldg4(p2 + offB);
    const float4 Btr = ldg4(t0 + offB), Btg = ldg4(t1 + offB), Btb = ldg4(t2 + offB);

    // halo edge columns (tid<136): 3 scalar loads
    float hv0 = 0.f, hv1 = 0.f, hv2 = 0.f;
    int hrow = 0, hside = 0, himg = 0;
    if (tid < 4 * HROWS) {
        himg = tid & 1;
        const int rr = tid >> 1;           // 0..67
        hside = rr >= HROWS;
        hrow  = hside ? rr - HROWS : rr;
        const int grow = min(max(th0 - 1 + hrow, 0), H - 1);
        const int gcol = hside ? min(tw0 + TW, W - 1) : max(tw0 - 1, 0);
        const float* ip = (himg ? t0 : p0) + (size_t)grow * W + gcol;
        hv0 = ip[0]; hv1 = ip[plane]; hv2 = ip[2 * plane];
    }

    // group C (rows 32..33, tid<32)
    float4 Cpr, Cpg, Cpb, Ctr, Ctg, Ctb;
    int rowC = 0, kC = 0;
    if (tid < 32) {
        const int gC = tid + 512;
        rowC = gC >> 4; kC = gC & 15;
        const int offC = (min(max(th0 - 1 + rowC, 0), H - 1)) * W + tw0 + 4 * kC;
        Cpr = ldg4(p0 + offC); Cpg = ldg4(p1 + offC); Cpb = ldg4(p2 + offC);
        Ctr = ldg4(t0 + offC); Ctg = ldg4(t1 + offC); Ctb = ldg4(t2 + offC);
    }

    // ---- consume (in issue order; vmcnt drains progressively) ----
    *reinterpret_cast<float4*>(&sp[rowA][4 + 4 * kA]) = gray4(Apr, Apg, Apb);
    *reinterpret_cast<float4*>(&st[rowA][4 + 4 * kA]) = gray4(Atr, Atg, Atb);
    *reinterpret_cast<float4*>(&sp[rowB][4 + 4 * kB]) = gray4(Bpr, Bpg, Bpb);
    *reinterpret_cast<float4*>(&st[rowB][4 + 4 * kB]) = gray4(Btr, Btg, Btb);

    if (tid < 4 * HROWS) {
        const float v = 0.299f * hv0 + 0.587f * hv1 + 0.114f * hv2;
        float (*dst)[LSTRIDE] = himg ? st : sp;
        dst[hrow][hside ? 68 : 3] = v;
    }
    if (tid < 32) {
        *reinterpret_cast<float4*>(&sp[rowC][4 + 4 * kC]) = gray4(Cpr, Cpg, Cpb);
        *reinterpret_cast<float4*>(&st[rowC][4 + 4 * kC]) = gray4(Ctr, Ctg, Ctb);
    }

    __syncthreads();

    // ---- Compute: vertical rolling 3x3 window, 8 rows per thread ----
    const int lw = tid & 63;               // column within tile
    const int q  = tid >> 6;               // wave index = vertical quarter
    const int r0 = q * 8;                  // top halo row for this strip
    const int c0 = lw + 3, c1 = lw + 4, c2 = lw + 5;

    float pa0 = sp[r0][c0],     pa1 = sp[r0][c1],     pa2 = sp[r0][c2];
    float pb0 = sp[r0 + 1][c0], pb1 = sp[r0 + 1][c1], pb2 = sp[r0 + 1][c2];
    float ta0 = st[r0][c0],     ta1 = st[r0][c1],     ta2 = st[r0][c2];
    float tb0 = st[r0 + 1][c0], tb1 = st[r0 + 1][c1], tb2 = st[r0 + 1][c2];

    float acc = 0.0f;
    #pragma unroll
    for (int r = 0; r < 8; ++r) {
        const int hr = r0 + r + 2;
        const float pc0 = sp[hr][c0], pc1 = sp[hr][c1], pc2 = sp[hr][c2];
        const float tc0 = st[hr][c0], tc1 = st[hr][c1], tc2 = st[hr][c2];

        float gx = ((pa2 - pa0) + 2.0f * (pb2 - pb0) + (pc2 - pc0)) * 0.125f;
        float gy = ((pc0 - pa0) + 2.0f * (pc1 - pa1) + (pc2 - pa2)) * 0.125f;
        const float pe = sqrtf(gx * gx + gy * gy + EPS);

        float hx = ((ta2 - ta0) + 2.0f * (tb2 - tb0) + (tc2 - tc0)) * 0.125f;
        float hy = ((tc0 - ta0) + 2.0f * (tc1 - ta1) + (tc2 - ta2)) * 0.125f;
        const float te = sqrtf(hx * hx + hy * hy + EPS);

        acc += fabsf(pe - te);

        pa0 = pb0; pa1 = pb1; pa2 = pb2;
        pb0 = pc0; pb1 = pc1; pb2 = pc2;
        ta0 = tb0; ta1 = tb1; ta2 = tb2;
        tb0 = tc0; tb1 = tc1; tb2 = tc2;
    }

    // ---- Block reduction -> one plain store per block (no atomics) ----
    #pragma unroll
    for (int off = 32; off > 0; off >>= 1)
        acc += __shfl_down(acc, off);

    __shared__ float wsum[NTHREADS / 64];
    if ((tid & 63) == 0) wsum[tid >> 6] = acc;
    __syncthreads();

    if (tid == 0) {
        partial[bid] = wsum[0] + wsum[1] + wsum[2] + wsum[3];
    }
}

__global__ __launch_bounds__(256) void reduce_kernel(
    const float* __restrict__ partial,
    float* __restrict__ out)
{
    const int tid = threadIdx.x;
    float acc = 0.0f;
    #pragma unroll
    for (int i = 0; i < NBLOCKS / 256; ++i)      // 8 coalesced loads
        acc += partial[tid + i * 256];

    #pragma unroll
    for (int off = 32; off > 0; off >>= 1)
        acc += __shfl_down(acc, off);

    __shared__ float wsum[4];
    if ((tid & 63) == 0) wsum[tid >> 6] = acc;
    __syncthreads();

    if (tid == 0) {
        const float s = wsum[0] + wsum[1] + wsum[2] + wsum[3];
        out[0] = s * (1.0f / (float)((size_t)B * H * W));  // 2^-22, exact
    }
}

extern "C" void kernel_launch(void* const* d_in, const int* in_sizes, int n_in,
                              void* d_out, int out_size, void* d_ws, size_t ws_size,
                              hipStream_t stream) {
    const float* pred = (const float*)d_in[0];
    const float* targ = (const float*)d_in[1];
    float* out = (float*)d_out;
    float* partial = (float*)d_ws;           // 2048 floats = 8 KB scratch

    edge_loss_kernel<<<NBLOCKS, NTHREADS, 0, stream>>>(pred, targ, partial);
    reduce_kernel<<<1, 256, 0, stream>>>(partial, out);
}